// Round 6
// baseline (32.872 us; speedup 1.0000x reference)
//
#include <hip/hip_runtime.h>
#include <hip/hip_bf16.h>

// MeanAggregator: out[b] = mean(features[neighbor_idx[b, :cnt[b]]]) if cnt>0
//                 else features[nodes[b]]
//
// Phase 0 (cache warm): each block streams a contiguous 16 KB slice of the
// feature table with coalesced f32x4 loads (kept live via asm, never stored).
// Chip-wide this fetches the 51.2 MB table into the memory-side 256 MiB L3
// in SEQUENTIAL order at near-peak DRAM efficiency; the random gathers below
// then hit L3 instead of issuing random 512B HBM fetches.
//
// Phase 1 (gather): 32 lanes per node-row (one f32x4 each); each 32-lane
// group handles TWO nodes, all 20 gathers issued back-to-back with
// predicated addresses (pads re-read base row = L1 hit, branchless).
// Output stored nontemporal (write-once stream).

#define B_NODES 50000
#define NUM_SAMPLE 10
#define D_FEAT 128
#define VEC_PER_ROW (D_FEAT / 4)   // 32 f32x4 per row
#define NODES_PER_BLOCK 16         // 8 groups x 2 nodes
#define TABLE_VEC4 3276800         // 100000 rows * 32 f32x4
#define WARM_PER_BLOCK 1024        // 4 iters * 256 threads

typedef float f32x4 __attribute__((ext_vector_type(4)));

__global__ __launch_bounds__(256) void mean_agg_kernel(
    const int* __restrict__ nodes,
    const int* __restrict__ neighbor_idx,
    const int* __restrict__ neighbor_count,
    const f32x4* __restrict__ features4,   // [N_NODES * 32]
    f32x4* __restrict__ out4)              // [B * 32]
{
    // ---- Phase 0: sequential table warm (populates memory-side L3). ----
    // Block b covers vec4 range [b*1024, b*1024+1024); max addr 3,199,999
    // < 3,276,800 so no guard needed (last 2.3% of table stays demand-fetched).
    f32x4 wsum = {0.f, 0.f, 0.f, 0.f};
    const int wbase = blockIdx.x * WARM_PER_BLOCK + threadIdx.x;
    #pragma unroll
    for (int i = 0; i < 4; ++i) {
        wsum += features4[wbase + i * 256];
    }
    // Keep the loads alive without storing anything (guide rule #17).
    asm volatile("" :: "v"(wsum.x), "v"(wsum.y), "v"(wsum.z), "v"(wsum.w));

    // ---- Phase 1: gather + mean. ----
    const int grp  = threadIdx.x >> 5;          // 0..7
    const int lane = threadIdx.x & 31;
    const int nA = blockIdx.x * NODES_PER_BLOCK + grp;        // first node
    const int nB = nA + 8;                                    // second node
    // B_NODES = 50000 = 3125 * 16, so nA/nB are always in range.

    const int cntA = neighbor_count[nA];
    const int cntB = neighbor_count[nB];
    const int ownA = nodes[nA];
    const int ownB = nodes[nB];

    const int2* a2 = (const int2*)(neighbor_idx + nA * NUM_SAMPLE);
    const int2* b2 = (const int2*)(neighbor_idx + nB * NUM_SAMPLE);
    const int2 a0 = a2[0], a1 = a2[1], a2_ = a2[2], a3 = a2[3], a4 = a2[4];
    const int2 b0 = b2[0], b1 = b2[1], b2_ = b2[2], b3 = b2[3], b4 = b2[4];
    const int idxA[NUM_SAMPLE] = {a0.x, a0.y, a1.x, a1.y, a2_.x, a2_.y, a3.x, a3.y, a4.x, a4.y};
    const int idxB[NUM_SAMPLE] = {b0.x, b0.y, b1.x, b1.y, b2_.x, b2_.y, b3.x, b3.y, b4.x, b4.y};

    // Padded/empty slots re-read the base row (hot in L1 after slot 0).
    const int baseA = (cntA == 0) ? ownA : idxA[0];
    const int baseB = (cntB == 0) ? ownB : idxB[0];

    // Issue all 20 gathers back-to-back: maximal per-wave MLP.
    f32x4 vA[NUM_SAMPLE], vB[NUM_SAMPLE];
    #pragma unroll
    for (int s = 0; s < NUM_SAMPLE; ++s) {
        const int eA = (s < cntA) ? idxA[s] : baseA;
        vA[s] = features4[eA * VEC_PER_ROW + lane];
    }
    #pragma unroll
    for (int s = 0; s < NUM_SAMPLE; ++s) {
        const int eB = (s < cntB) ? idxB[s] : baseB;
        vB[s] = features4[eB * VEC_PER_ROW + lane];
    }

    // Slot 0 always has weight 1 (idx[0] if cnt>0, own row if cnt==0).
    f32x4 accA = vA[0];
    #pragma unroll
    for (int s = 1; s < NUM_SAMPLE; ++s) {
        const float w = (s < cntA) ? 1.0f : 0.0f;
        accA += w * vA[s];
    }
    accA *= 1.0f / (float)((cntA > 1) ? cntA : 1);
    __builtin_nontemporal_store(accA, &out4[nA * VEC_PER_ROW + lane]);

    f32x4 accB = vB[0];
    #pragma unroll
    for (int s = 1; s < NUM_SAMPLE; ++s) {
        const float w = (s < cntB) ? 1.0f : 0.0f;
        accB += w * vB[s];
    }
    accB *= 1.0f / (float)((cntB > 1) ? cntB : 1);
    __builtin_nontemporal_store(accB, &out4[nB * VEC_PER_ROW + lane]);
}

extern "C" void kernel_launch(void* const* d_in, const int* in_sizes, int n_in,
                              void* d_out, int out_size, void* d_ws, size_t ws_size,
                              hipStream_t stream) {
    const int*   nodes          = (const int*)d_in[0];
    const int*   neighbor_idx   = (const int*)d_in[1];
    const int*   neighbor_count = (const int*)d_in[2];
    const f32x4* features4      = (const f32x4*)d_in[3];
    f32x4*       out4           = (f32x4*)d_out;

    const int grid = (B_NODES + NODES_PER_BLOCK - 1) / NODES_PER_BLOCK;  // 3125
    mean_agg_kernel<<<grid, 256, 0, stream>>>(nodes, neighbor_idx, neighbor_count,
                                              features4, out4);
}

// Round 7
// 26.914 us; speedup vs baseline: 1.2214x; 1.2214x over previous
//
#include <hip/hip_runtime.h>
#include <hip/hip_bf16.h>

// MeanAggregator: out[b] = mean(features[neighbor_idx[b, :cnt[b]]]) if cnt>0
//                 else features[nodes[b]]
//
// Best measured structure (R5, 26.6us):
// 32 lanes per node-row (one f32x4 of the 128-float row each).
// Each 32-lane group handles TWO nodes: all 20 gathers issue back-to-back
// (predicated ADDRESS, not exec mask -- pads re-read the base row = L1 hit,
// branchless) before any accumulate. Block 256 threads = 16 nodes.
// Output stored nontemporal (write-once stream).
//
// Measured regime notes (R2/R5/R6 probes): gathers are L3-resident on timed
// replays (warming the L3 regressed 26.6->32.9us); ~62MB random-granule
// fetch + 25MB stream write move at ~2.4TB/s effective = the 512B-random
// fabric ceiling. Exec-masked pads (R3) and L3 warming (R6) both regressed.

#define B_NODES 50000
#define NUM_SAMPLE 10
#define D_FEAT 128
#define VEC_PER_ROW (D_FEAT / 4)   // 32 f32x4 per row
#define NODES_PER_BLOCK 16         // 8 groups x 2 nodes

typedef float f32x4 __attribute__((ext_vector_type(4)));

__global__ __launch_bounds__(256) void mean_agg_kernel(
    const int* __restrict__ nodes,
    const int* __restrict__ neighbor_idx,
    const int* __restrict__ neighbor_count,
    const f32x4* __restrict__ features4,   // [N_NODES * 32]
    f32x4* __restrict__ out4)              // [B * 32]
{
    const int grp  = threadIdx.x >> 5;          // 0..7
    const int lane = threadIdx.x & 31;
    const int nA = blockIdx.x * NODES_PER_BLOCK + grp;        // first node
    const int nB = nA + 8;                                    // second node
    // B_NODES = 50000 = 3125 * 16, so nA/nB are always in range.

    const int cntA = neighbor_count[nA];
    const int cntB = neighbor_count[nB];
    const int ownA = nodes[nA];
    const int ownB = nodes[nB];

    const int2* a2 = (const int2*)(neighbor_idx + nA * NUM_SAMPLE);
    const int2* b2 = (const int2*)(neighbor_idx + nB * NUM_SAMPLE);
    const int2 a0 = a2[0], a1 = a2[1], a2_ = a2[2], a3 = a2[3], a4 = a2[4];
    const int2 b0 = b2[0], b1 = b2[1], b2_ = b2[2], b3 = b2[3], b4 = b2[4];
    const int idxA[NUM_SAMPLE] = {a0.x, a0.y, a1.x, a1.y, a2_.x, a2_.y, a3.x, a3.y, a4.x, a4.y};
    const int idxB[NUM_SAMPLE] = {b0.x, b0.y, b1.x, b1.y, b2_.x, b2_.y, b3.x, b3.y, b4.x, b4.y};

    // Padded/empty slots re-read the base row (hot in L1 after slot 0).
    const int baseA = (cntA == 0) ? ownA : idxA[0];
    const int baseB = (cntB == 0) ? ownB : idxB[0];

    // Issue all 20 gathers back-to-back: maximal per-wave MLP.
    f32x4 vA[NUM_SAMPLE], vB[NUM_SAMPLE];
    #pragma unroll
    for (int s = 0; s < NUM_SAMPLE; ++s) {
        const int eA = (s < cntA) ? idxA[s] : baseA;
        vA[s] = features4[eA * VEC_PER_ROW + lane];
    }
    #pragma unroll
    for (int s = 0; s < NUM_SAMPLE; ++s) {
        const int eB = (s < cntB) ? idxB[s] : baseB;
        vB[s] = features4[eB * VEC_PER_ROW + lane];
    }

    // Slot 0 always has weight 1 (idx[0] if cnt>0, own row if cnt==0).
    f32x4 accA = vA[0];
    #pragma unroll
    for (int s = 1; s < NUM_SAMPLE; ++s) {
        const float w = (s < cntA) ? 1.0f : 0.0f;
        accA += w * vA[s];
    }
    accA *= 1.0f / (float)((cntA > 1) ? cntA : 1);
    __builtin_nontemporal_store(accA, &out4[nA * VEC_PER_ROW + lane]);

    f32x4 accB = vB[0];
    #pragma unroll
    for (int s = 1; s < NUM_SAMPLE; ++s) {
        const float w = (s < cntB) ? 1.0f : 0.0f;
        accB += w * vB[s];
    }
    accB *= 1.0f / (float)((cntB > 1) ? cntB : 1);
    __builtin_nontemporal_store(accB, &out4[nB * VEC_PER_ROW + lane]);
}

extern "C" void kernel_launch(void* const* d_in, const int* in_sizes, int n_in,
                              void* d_out, int out_size, void* d_ws, size_t ws_size,
                              hipStream_t stream) {
    const int*   nodes          = (const int*)d_in[0];
    const int*   neighbor_idx   = (const int*)d_in[1];
    const int*   neighbor_count = (const int*)d_in[2];
    const f32x4* features4      = (const f32x4*)d_in[3];
    f32x4*       out4           = (f32x4*)d_out;

    const int grid = (B_NODES + NODES_PER_BLOCK - 1) / NODES_PER_BLOCK;  // 3125
    mean_agg_kernel<<<grid, 256, 0, stream>>>(nodes, neighbor_idx, neighbor_count,
                                              features4, out4);
}